// Round 2
// baseline (418.998 us; speedup 1.0000x reference)
//
#include <hip/hip_runtime.h>

#define MAX_LEN 32
#define NBINS 63          // 2*MAX_LEN - 1
#define D_MODEL 128
#define B_SZ 2
#define L_SZ 512

// Native clang vector type so __builtin_nontemporal_* accepts it
// (HIP's float4 is a class and is rejected by the builtin).
typedef float v4f __attribute__((ext_vector_type(4)));

// Fused table: T[bin*128 + d] = W[d][bin] + b[d].  63*128 fp32 = 32 KB.
// __device__ global (module-scope) so we don't depend on ws_size; rebuilt
// every launch so re-poisoning doesn't matter.
__device__ float g_T[NBINS * D_MODEL];

__global__ __launch_bounds__(256)
void build_table_kernel(const float* __restrict__ W, const float* __restrict__ bias) {
    int t = blockIdx.x * blockDim.x + threadIdx.x;   // 0 .. 63*128-1
    if (t >= NBINS * D_MODEL) return;
    int bin = t >> 7;          // t / 128
    int d   = t & (D_MODEL-1); // t % 128
    // W is [d_model, 63] row-major: W[d][bin] = W[d*63 + bin]
    g_T[t] = W[d * NBINS + bin] + bias[d];
}

__global__ __launch_bounds__(256)
void add_relpos_kernel(const v4f* __restrict__ x, v4f* __restrict__ out, int total4) {
    int g = blockIdx.x * blockDim.x + threadIdx.x;
    if (g >= total4) return;

    // g indexes float4s of [B, L, L, D/4=32]
    int d4 = g & 31;               // position along D (in float4 units)
    int ij = g >> 5;               // (b*L + i)*L + j
    int j  = ij & (L_SZ - 1);
    int i  = (ij >> 9) & (L_SZ - 1);

    int rel = i - j;
    rel = rel < -(MAX_LEN - 1) ? -(MAX_LEN - 1) : rel;
    rel = rel >  (MAX_LEN - 1) ?  (MAX_LEN - 1) : rel;
    int bin = rel + (MAX_LEN - 1);

    // Table row: 512 B aligned, v4f load; hits L1/L2 (32 KB table)
    const v4f* Trow = reinterpret_cast<const v4f*>(&g_T[bin * D_MODEL]);
    v4f t  = Trow[d4];

    // x / out are streamed once: nontemporal to avoid polluting L2/L3
    v4f xv = __builtin_nontemporal_load(&x[g]);
    v4f r  = xv + t;
    __builtin_nontemporal_store(r, &out[g]);
}

extern "C" void kernel_launch(void* const* d_in, const int* in_sizes, int n_in,
                              void* d_out, int out_size, void* d_ws, size_t ws_size,
                              hipStream_t stream) {
    const float* x    = (const float*)d_in[0];   // [2,512,512,128] fp32
    // d_in[1] = idx (int64), unused by the reference forward
    const float* W    = (const float*)d_in[2];   // [128, 63] fp32
    const float* bias = (const float*)d_in[3];   // [128] fp32
    float* out = (float*)d_out;

    // Stage 1: build fused W^T+b table (8064 elements)
    build_table_kernel<<<(NBINS * D_MODEL + 255) / 256, 256, 0, stream>>>(W, bias);

    // Stage 2: out = x + T[bin(i,j)] broadcast
    const int total4 = (B_SZ * L_SZ * L_SZ * D_MODEL) / 4;  // 16,777,216
    add_relpos_kernel<<<total4 / 256, 256, 0, stream>>>(
        reinterpret_cast<const v4f*>(x),
        reinterpret_cast<v4f*>(out),
        total4);
}